// Round 7
// baseline (60.662 us; speedup 1.0000x reference)
//
#include <hip/hip_runtime.h>
#include <math.h>

// CTC forward loss, Keras ctc_batch_cost semantics.
// B=1024, T=256, C=128, L=64, S=2L+1=129, blank=C-1=127.
// Prob-domain forward DP (no per-step transcendentals), power-of-2 rescale
// every 8 steps. ITEM-LEVEL pipeline: 256 blocks, 4 batch items each,
// double-buffered LDS q-tables. Waves 1-7 stream item i+1 while wave 0 runs
// the full DP of item i. One __syncthreads per item.
#define BATCH 1024
#define TT    256
#define CC    128
#define LL    64
#define EPSV  (1e-7f)
#define ITEMS 4
#define NBLK  (BATCH / ITEMS)

typedef float f32x4 __attribute__((ext_vector_type(4)));

// DPP ctrl: row_shr:N = 0x110+N, row_bcast:15 = 0x142, row_bcast:31 = 0x143,
// wave_rol:1 = 0x134.
template <int CTRL>
__device__ __forceinline__ float dpp0(float x) {   // invalid lanes -> 0
    return __int_as_float(__builtin_amdgcn_update_dpp(0, __float_as_int(x), CTRL, 0xF, 0xF, true));
}
template <int CTRL>
__device__ __forceinline__ float dppS(float x) {   // invalid lanes -> self
    return __int_as_float(__builtin_amdgcn_update_dpp(__float_as_int(x), __float_as_int(x), CTRL, 0xF, 0xF, false));
}
__device__ __forceinline__ float rol1_f(float x) { // lane i <- lane (i-1)&63
    return __int_as_float(__builtin_amdgcn_update_dpp(__float_as_int(x), __float_as_int(x), 0x134, 0xF, 0xF, false));
}
__device__ __forceinline__ int rol1_i(int x) {
    return __builtin_amdgcn_update_dpp(x, x, 0x134, 0xF, 0xF, false);
}
__device__ __forceinline__ float rdlane(float x, int l) {
    return __int_as_float(__builtin_amdgcn_readlane(__float_as_int(x), l));
}
__device__ __forceinline__ float wave_max_bcast(float m) {
    m = fmaxf(m, dppS<0x111>(m));
    m = fmaxf(m, dppS<0x112>(m));
    m = fmaxf(m, dppS<0x114>(m));
    m = fmaxf(m, dppS<0x118>(m));
    m = fmaxf(m, dppS<0x142>(m));
    m = fmaxf(m, dppS<0x143>(m));
    return rdlane(m, 63);
}
__device__ __forceinline__ unsigned f2h(float x) { // fp32 -> fp16 bits (RTN)
    _Float16 h = (_Float16)x;
    unsigned short u; __builtin_memcpy(&u, &h, 2);
    return (unsigned)u;
}
__device__ __forceinline__ float h2f(unsigned short u) {
    _Float16 h; __builtin_memcpy(&h, &u, 2);
    return (float)h;
}

// Stream one item's y_pred rows into the fp16 q-table.
// Each float4 load covers 2 rows (lanes 0-31 -> row 2*r2, lanes 32-63 -> 2*r2+1).
// This wave handles row-pairs r2 = start + STRIDE*i, i in [0, NPAIRS), r2 < 128.
template <int NPAIRS, int STRIDE, int DEPTH>
__device__ __forceinline__ void stream_item(const float* __restrict__ base, // yp(item)+off
                                            int start, int lab, int lane,
                                            unsigned short (* __restrict__ qt)[66],
                                            float* __restrict__ qb,
                                            float* __restrict__ lzslot) {
    const int  srcA   = lab >> 2;
    const int  srcB   = 32 + srcA;
    const bool hiPair = (lab & 2) != 0;
    const bool hiHalf = (lab & 1) != 0;

    float zacc = 0.0f;                 // meaningful on lanes 31 / 63
    f32x4 v[DEPTH];
    #pragma unroll
    for (int d = 0; d < DEPTH; ++d) {
        int r2 = start + STRIDE * d; r2 = (r2 < 128) ? r2 : 127;
        v[d] = *(const f32x4*)(base + 256 * r2);
    }
    #pragma unroll
    for (int i = 0; i < NPAIRS; ++i) {
        const int  r2i   = start + STRIDE * i;
        const bool valid = (r2i < 128);
        const int  r2    = valid ? r2i : 127;
        f32x4 x = v[i % DEPTH];
        if (i + DEPTH < NPAIRS) {      // prefetch into the freed slot
            int rn = start + STRIDE * (i + DEPTH); rn = (rn < 128) ? rn : 127;
            v[i % DEPTH] = *(const f32x4*)(base + 256 * rn);
        }
        const int tA = 2 * r2, tB = tA + 1;
        float q0 = x[0] + EPSV, q1 = x[1] + EPSV;
        float q2 = x[2] + EPSV, q3 = x[3] + EPSV;
        // half-wave reduce: row-A total -> lane 31, row-B total -> lane 63
        float s = (q0 + q1) + (q2 + q3);
        s += dpp0<0x111>(s);
        s += dpp0<0x112>(s);
        s += dpp0<0x114>(s);
        s += dpp0<0x118>(s);
        s += dpp0<0x142>(s);
        if (valid) zacc += __logf(s);
        // pack own 4 cols to fp16 pairs, gather via register shuffles
        int i01 = (int)(f2h(q0) | (f2h(q1) << 16));
        int i23 = (int)(f2h(q2) | (f2h(q3) << 16));
        int gA01 = __shfl(i01, srcA), gA23 = __shfl(i23, srcA);
        int gB01 = __shfl(i01, srcB), gB23 = __shfl(i23, srcB);
        int sA = hiPair ? gA23 : gA01;
        int sB = hiPair ? gB23 : gB01;
        qt[tA][lane] = (unsigned short)(hiHalf ? ((unsigned)sA >> 16) : (sA & 0xFFFF));
        qt[tB][lane] = (unsigned short)(hiHalf ? ((unsigned)sB >> 16) : (sB & 0xFFFF));
        if ((lane & 31) == 31) qb[tA + (lane >> 5)] = q3;   // col 127 == blank
    }
    float z31 = rdlane(zacc, 31), z63 = rdlane(zacc, 63);
    if (lane == 0) *lzslot = z31 + z63;
}

// Full 256-step DP for one item from its staged q-table; writes out[bglob].
__device__ __forceinline__ void run_dp(int bglob, int lane,
                                       const int* __restrict__ y_true,
                                       const unsigned short (* __restrict__ qt)[66],
                                       const float* __restrict__ qb_,
                                       const float* __restrict__ lz, int lzFirst,
                                       float* __restrict__ out) {
    const int   lab   = y_true[bglob * LL + lane];
    const int   labm1 = rol1_i(lab);
    const float mskip = (lane >= 1 && lab != labm1) ? 1.0f : 0.0f;
    const bool  l0 = (lane == 0);

    // t=0 init: alpha[0]=q0[blank], alpha[1]=q0[yt[0]], rest 0.
    float a0 = l0 ? qb_[0] : 0.0f;            // even state 2*lane
    float a1 = l0 ? h2f(qt[0][lane]) : 0.0f;  // odd state 2*lane+1
    float aX = 0.0f;                           // state 128 (lane 0 only)
    int Esum = 0;

    float qbv[8], qlv[8];
    #pragma unroll
    for (int i = 0; i < 8; ++i) {             // preload t = 1..8
        qbv[i] = qb_[1 + i];
        qlv[i] = h2f(qt[1 + i][lane]);
    }
    for (int t0 = 1; t0 + 8 <= TT; t0 += 8) { // 31 chunks: t = 1..248
        float qbn[8], qln[8];
        #pragma unroll
        for (int i = 0; i < 8; ++i) {         // prefetch next chunk (clamped)
            int tn = t0 + 8 + i; tn = (tn < TT) ? tn : (TT - 1);
            qbn[i] = qb_[tn];
            qln[i] = h2f(qt[tn][lane]);
        }
        #pragma unroll
        for (int i = 0; i < 8; ++i) {
            float nb  = rol1_f(a1);           // alpha[2*lane-1]
            float na0 = (a0 + (l0 ? 0.0f : nb)) * qbv[i];
            float na1 = fmaf(mskip, nb, a0 + a1) * qlv[i];
            aX = l0 ? (aX + nb) * qbv[i] : 0.0f;
            a0 = na0; a1 = na1;
        }
        float m = fmaxf(fmaxf(a0, a1), aX);   // power-of-2 rescale per chunk
        float mall = wave_max_bcast(m);
        int ex = (int)((__float_as_uint(mall) >> 23) & 0xFF);
        int e  = 127 - ex;
        float sc = __uint_as_float((unsigned)(127 + e) << 23);
        a0 *= sc; a1 *= sc; aX *= sc;
        Esum += e;
        #pragma unroll
        for (int i = 0; i < 8; ++i) { qbv[i] = qbn[i]; qlv[i] = qln[i]; }
    }
    #pragma unroll
    for (int i = 0; i < 7; ++i) {             // epilogue t = 249..255
        float nb  = rol1_f(a1);
        float na0 = (a0 + (l0 ? 0.0f : nb)) * qbv[i];
        float na1 = fmaf(mskip, nb, a0 + a1) * qlv[i];
        aX = l0 ? (aX + nb) * qbv[i] : 0.0f;
        a0 = na0; a1 = na1;
    }
    float LZ = 0.0f;
    for (int w = lzFirst; w < 8; ++w) LZ += lz[w];
    float a127 = rdlane(a1, 63);
    if (lane == 0) {
        out[bglob] = LZ + (float)Esum * 0.69314718055994531f - __logf(aX + a127);
    }
}

__global__ __launch_bounds__(512, 2) void ctc_fwd_kernel(const int* __restrict__ y_true,
                                                         const float* __restrict__ y_pred,
                                                         float* __restrict__ out) {
    __shared__ unsigned short qtab[2][TT][66];
    __shared__ float qblank[2][TT];
    __shared__ float logZpart[2][8];

    const int tid  = threadIdx.x;
    const int wv   = tid >> 6;
    const int lane = tid & 63;
    const int b0   = blockIdx.x * ITEMS;
    const int off  = ((lane >> 5) << 7) + ((lane & 31) << 2);

    // Prologue: all 8 waves stream item 0 into buffer 0 (16 pairs each, stride 8).
    {
        int lab = y_true[b0 * LL + lane];
        stream_item<16, 8, 6>(y_pred + (size_t)b0 * (TT * CC) + off, wv, lab, lane,
                              qtab[0], qblank[0], &logZpart[0][wv]);
    }
    __syncthreads();

    for (int i = 0; i < ITEMS; ++i) {
        const int cur = i & 1;
        if (wv > 0 && i + 1 < ITEMS) {
            // Waves 1-7 stream item i+1 (19 pairs each, stride 7, clamped).
            const int bnx = b0 + i + 1;
            int lab = y_true[bnx * LL + lane];
            stream_item<19, 7, 6>(y_pred + (size_t)bnx * (TT * CC) + off, wv - 1, lab, lane,
                                  qtab[cur ^ 1], qblank[cur ^ 1], &logZpart[cur ^ 1][wv]);
        }
        if (wv == 0) {
            __builtin_amdgcn_s_setprio(1);
            run_dp(b0 + i, lane, y_true, qtab[cur], qblank[cur],
                   logZpart[cur], (i == 0) ? 0 : 1, out);
            __builtin_amdgcn_s_setprio(0);
        }
        if (i + 1 < ITEMS) __syncthreads();
    }
}

extern "C" void kernel_launch(void* const* d_in, const int* in_sizes, int n_in,
                              void* d_out, int out_size, void* d_ws, size_t ws_size,
                              hipStream_t stream) {
    const int*   y_true = (const int*)d_in[0];
    const float* y_pred = (const float*)d_in[1];
    float*       out    = (float*)d_out;
    ctc_fwd_kernel<<<NBLK, 512, 0, stream>>>(y_true, y_pred, out);
}

// Round 8
// 49.098 us; speedup vs baseline: 1.2355x; 1.2355x over previous
//
#include <hip/hip_runtime.h>
#include <math.h>

// CTC forward loss, Keras ctc_batch_cost semantics.
// B=1024, T=256, C=128, L=64, S=2L+1=129, blank=C-1=127.
// TWO-KERNEL split:
//   A) pure streaming at max occupancy: build fp16 q-tables + qblank + logZ
//      partials in d_ws (no LDS, no DP coupling).
//   B) 1024 one-wave blocks run the 256-step prob-domain register DP from the
//      (L3-resident) tables with 2-chunk-ahead register prefetch.
// Prob-domain DP, power-of-2 rescale every 8 steps (31 rescales) — numerics
// identical to the round-5 kernel. Fallback single kernel if ws too small.
#define BATCH 1024
#define TT    256
#define CC    128
#define LL    64
#define EPSV  (1e-7f)

#define QT_BYTES  ((size_t)BATCH * TT * 64 * 2)          // 33,554,432
#define QB_OFF    QT_BYTES
#define QB_BYTES  ((size_t)BATCH * TT * 4)               //  1,048,576
#define LZ_OFF    (QB_OFF + QB_BYTES)
#define LZ_BYTES  ((size_t)BATCH * 8 * 4)                //     32,768
#define WS_NEEDED (LZ_OFF + LZ_BYTES)

typedef float f32x4 __attribute__((ext_vector_type(4)));

// DPP ctrl: row_shr:N = 0x110+N, row_bcast:15 = 0x142, row_bcast:31 = 0x143,
// wave_rol:1 = 0x134.
template <int CTRL>
__device__ __forceinline__ float dpp0(float x) {   // invalid lanes -> 0
    return __int_as_float(__builtin_amdgcn_update_dpp(0, __float_as_int(x), CTRL, 0xF, 0xF, true));
}
template <int CTRL>
__device__ __forceinline__ float dppS(float x) {   // invalid lanes -> self
    return __int_as_float(__builtin_amdgcn_update_dpp(__float_as_int(x), __float_as_int(x), CTRL, 0xF, 0xF, false));
}
__device__ __forceinline__ float rol1_f(float x) { // lane i <- lane (i-1)&63
    return __int_as_float(__builtin_amdgcn_update_dpp(__float_as_int(x), __float_as_int(x), 0x134, 0xF, 0xF, false));
}
__device__ __forceinline__ int rol1_i(int x) {
    return __builtin_amdgcn_update_dpp(x, x, 0x134, 0xF, 0xF, false);
}
__device__ __forceinline__ float rdlane(float x, int l) {
    return __int_as_float(__builtin_amdgcn_readlane(__float_as_int(x), l));
}
__device__ __forceinline__ float wave_max_bcast(float m) {
    m = fmaxf(m, dppS<0x111>(m));
    m = fmaxf(m, dppS<0x112>(m));
    m = fmaxf(m, dppS<0x114>(m));
    m = fmaxf(m, dppS<0x118>(m));
    m = fmaxf(m, dppS<0x142>(m));
    m = fmaxf(m, dppS<0x143>(m));
    return rdlane(m, 63);
}
__device__ __forceinline__ unsigned f2h(float x) { // fp32 -> fp16 bits (RTN)
    _Float16 h = (_Float16)x;
    unsigned short u; __builtin_memcpy(&u, &h, 2);
    return (unsigned)u;
}
__device__ __forceinline__ float h2f(unsigned short u) {
    _Float16 h; __builtin_memcpy(&h, &u, 2);
    return (float)h;
}

// ===================== Kernel A: streaming table build =====================
__global__ __launch_bounds__(512, 8) void ctc_stage_kernel(const int* __restrict__ y_true,
                                                           const float* __restrict__ y_pred,
                                                           unsigned short* __restrict__ qt_g,
                                                           float* __restrict__ qb_g,
                                                           float* __restrict__ lz_g) {
    const int b    = blockIdx.x;
    const int tid  = threadIdx.x;
    const int wv   = tid >> 6;
    const int lane = tid & 63;

    const float* yp = y_pred + (size_t)b * (TT * CC);
    const int lab  = y_true[b * LL + lane];
    const int srcA = lab >> 2;
    const int srcB = 32 + srcA;
    const bool hiPair = (lab & 2) != 0;
    const bool hiHalf = (lab & 1) != 0;

    // float4 covers 2 rows: lanes 0-31 -> row 2*r2, lanes 32-63 -> row 2*r2+1.
    const int off = ((lane >> 5) << 7) + ((lane & 31) << 2);
    const float* base = yp + off;
    unsigned short* qt = qt_g + (size_t)b * (TT * 64);
    float* qb = qb_g + b * TT;

    // Wave wv handles row-pairs r2 = wv + 8*i, i = 0..15; 6-deep prefetch.
    float zacc = 0.0f;                 // meaningful on lanes 31 / 63
    f32x4 v[6];
    #pragma unroll
    for (int d = 0; d < 6; ++d)
        v[d] = __builtin_nontemporal_load((const f32x4*)(base + 256 * (wv + 8 * d)));

    #pragma unroll
    for (int i = 0; i < 16; ++i) {
        f32x4 x = v[i % 6];
        if (i + 6 < 16)
            v[i % 6] = __builtin_nontemporal_load((const f32x4*)(base + 256 * (wv + 8 * (i + 6))));
        const int r2 = wv + 8 * i;
        const int tA = 2 * r2, tB = tA + 1;
        float q0 = x[0] + EPSV, q1 = x[1] + EPSV;
        float q2 = x[2] + EPSV, q3 = x[3] + EPSV;
        // half-wave reduce: row-A total -> lane 31, row-B total -> lane 63
        float s = (q0 + q1) + (q2 + q3);
        s += dpp0<0x111>(s);
        s += dpp0<0x112>(s);
        s += dpp0<0x114>(s);
        s += dpp0<0x118>(s);
        s += dpp0<0x142>(s);
        zacc += __logf(s);             // garbage off lanes 31/63 (finite)
        // pack own 4 cols to fp16 pairs, gather via register shuffles
        int i01 = (int)(f2h(q0) | (f2h(q1) << 16));
        int i23 = (int)(f2h(q2) | (f2h(q3) << 16));
        int gA01 = __shfl(i01, srcA), gA23 = __shfl(i23, srcA);
        int gB01 = __shfl(i01, srcB), gB23 = __shfl(i23, srcB);
        int sA = hiPair ? gA23 : gA01;
        int sB = hiPair ? gB23 : gB01;
        qt[tA * 64 + lane] = (unsigned short)(hiHalf ? ((unsigned)sA >> 16) : (sA & 0xFFFF));
        qt[tB * 64 + lane] = (unsigned short)(hiHalf ? ((unsigned)sB >> 16) : (sB & 0xFFFF));
        if ((lane & 31) == 31) qb[tA + (lane >> 5)] = q3;   // col 127 == blank
    }
    float z31 = rdlane(zacc, 31), z63 = rdlane(zacc, 63);
    if (lane == 0) lz_g[b * 8 + wv] = z31 + z63;
}

// ===================== Kernel B: per-item register DP =====================
__device__ __forceinline__ void load_chunk8(const unsigned short* __restrict__ qt,
                                            const float* __restrict__ qb,
                                            int lane, int t0,
                                            float (&qbo)[8], float (&qlo)[8]) {
    #pragma unroll
    for (int i = 0; i < 8; ++i) {
        int t = t0 + i; t = (t < TT) ? t : (TT - 1);
        qbo[i] = qb[t];
        qlo[i] = h2f(qt[t * 64 + lane]);
    }
}
__device__ __forceinline__ void steps8(const float (&qbv)[8], const float (&qlv)[8],
                                       float& a0, float& a1, float& aX,
                                       float mskip, bool l0, int& Esum) {
    #pragma unroll
    for (int i = 0; i < 8; ++i) {
        float nb  = rol1_f(a1);               // alpha[2*lane-1]
        float na0 = (a0 + (l0 ? 0.0f : nb)) * qbv[i];
        float na1 = fmaf(mskip, nb, a0 + a1) * qlv[i];
        aX = l0 ? (aX + nb) * qbv[i] : 0.0f;  // state 128
        a0 = na0; a1 = na1;
    }
    float m = fmaxf(fmaxf(a0, a1), aX);       // power-of-2 rescale per chunk
    float mall = wave_max_bcast(m);
    int ex = (int)((__float_as_uint(mall) >> 23) & 0xFF);
    int e  = 127 - ex;
    float sc = __uint_as_float((unsigned)(127 + e) << 23);
    a0 *= sc; a1 *= sc; aX *= sc;
    Esum += e;
}

__global__ __launch_bounds__(64, 4) void ctc_dp_kernel(const int* __restrict__ y_true,
                                                       const unsigned short* __restrict__ qt_g,
                                                       const float* __restrict__ qb_g,
                                                       const float* __restrict__ lz_g,
                                                       float* __restrict__ out) {
    const int b    = blockIdx.x;
    const int lane = threadIdx.x;
    const unsigned short* qt = qt_g + (size_t)b * (TT * 64);
    const float* qb = qb_g + b * TT;

    const int   lab   = y_true[b * LL + lane];
    const int   labm1 = rol1_i(lab);
    const float mskip = (lane >= 1 && lab != labm1) ? 1.0f : 0.0f;
    const bool  l0 = (lane == 0);

    // t=0 init: alpha[0]=q0[blank], alpha[1]=q0[yt[0]], rest 0.
    float a0 = l0 ? qb[0] : 0.0f;
    float a1 = l0 ? h2f(qt[lane]) : 0.0f;
    float aX = 0.0f;
    int Esum = 0;

    float qbA[8], qlA[8], qbB[8], qlB[8], qbC[8], qlC[8], qbD[8], qlD[8];
    load_chunk8(qt, qb, lane, 1, qbA, qlA);   // chunk 0: t=1..8
    load_chunk8(qt, qb, lane, 9, qbB, qlB);   // chunk 1: t=9..16

    for (int it = 0; it < 15; ++it) {         // chunks 2it, 2it+1
        load_chunk8(qt, qb, lane, 17 + 16 * it, qbC, qlC);   // chunk 2it+2
        steps8(qbA, qlA, a0, a1, aX, mskip, l0, Esum);
        load_chunk8(qt, qb, lane, 25 + 16 * it, qbD, qlD);   // chunk 2it+3
        steps8(qbB, qlB, a0, a1, aX, mskip, l0, Esum);
        #pragma unroll
        for (int i = 0; i < 8; ++i) {
            qbA[i] = qbC[i]; qlA[i] = qlC[i];
            qbB[i] = qbD[i]; qlB[i] = qlD[i];
        }
    }
    steps8(qbA, qlA, a0, a1, aX, mskip, l0, Esum);  // chunk 30: t=241..248
    #pragma unroll
    for (int i = 0; i < 7; ++i) {                   // epilogue t=249..255
        float nb  = rol1_f(a1);
        float na0 = (a0 + (l0 ? 0.0f : nb)) * qbB[i];
        float na1 = fmaf(mskip, nb, a0 + a1) * qlB[i];
        aX = l0 ? (aX + nb) * qbB[i] : 0.0f;
        a0 = na0; a1 = na1;
    }
    float LZ = 0.0f;
    #pragma unroll
    for (int w = 0; w < 8; ++w) LZ += lz_g[b * 8 + w];
    float a127 = rdlane(a1, 63);
    if (lane == 0)
        out[b] = LZ + (float)Esum * 0.69314718055994531f - __logf(aX + a127);
}

// ===================== Fallback: round-5 single kernel =====================
__global__ __launch_bounds__(512, 8) void ctc_fwd_kernel(const int* __restrict__ y_true,
                                                         const float* __restrict__ y_pred,
                                                         float* __restrict__ out) {
    __shared__ unsigned short qtab[TT][66];
    __shared__ float qblank[TT];
    __shared__ float logZpart[8];

    const int b    = blockIdx.x;
    const int tid  = threadIdx.x;
    const int wv   = tid >> 6;
    const int lane = tid & 63;

    const float* yp = y_pred + (size_t)b * (TT * CC);
    const int lab  = y_true[b * LL + lane];
    const int srcA = lab >> 2;
    const int srcB = 32 + srcA;
    const bool hiPair = (lab & 2) != 0;
    const bool hiHalf = (lab & 1) != 0;

    const int off = ((lane >> 5) << 7) + ((lane & 31) << 2);
    const float* base = yp + off;

    float zacc = 0.0f;
    f32x4 v[4];
    #pragma unroll
    for (int j = 0; j < 4; ++j)
        v[j] = __builtin_nontemporal_load((const f32x4*)(base + 256 * (wv + 8 * j)));

    for (int g = 0; g < 4; ++g) {
        f32x4 vn[4];
        if (g < 3) {
            #pragma unroll
            for (int j = 0; j < 4; ++j)
                vn[j] = __builtin_nontemporal_load((const f32x4*)(base + 256 * (wv + 32 * (g + 1) + 8 * j)));
        }
        #pragma unroll
        for (int j = 0; j < 4; ++j) {
            const int r2 = wv + 32 * g + 8 * j;
            const int tA = 2 * r2, tB = tA + 1;
            float q0 = v[j][0] + EPSV, q1 = v[j][1] + EPSV;
            float q2 = v[j][2] + EPSV, q3 = v[j][3] + EPSV;
            float s = (q0 + q1) + (q2 + q3);
            s += dpp0<0x111>(s);
            s += dpp0<0x112>(s);
            s += dpp0<0x114>(s);
            s += dpp0<0x118>(s);
            s += dpp0<0x142>(s);
            zacc += __logf(s);
            int i01 = (int)(f2h(q0) | (f2h(q1) << 16));
            int i23 = (int)(f2h(q2) | (f2h(q3) << 16));
            int gA01 = __shfl(i01, srcA), gA23 = __shfl(i23, srcA);
            int gB01 = __shfl(i01, srcB), gB23 = __shfl(i23, srcB);
            int sA = hiPair ? gA23 : gA01;
            int sB = hiPair ? gB23 : gB01;
            qtab[tA][lane] = (unsigned short)(hiHalf ? ((unsigned)sA >> 16) : (sA & 0xFFFF));
            qtab[tB][lane] = (unsigned short)(hiHalf ? ((unsigned)sB >> 16) : (sB & 0xFFFF));
            if ((lane & 31) == 31) qblank[tA + (lane >> 5)] = q3;
        }
        #pragma unroll
        for (int j = 0; j < 4; ++j) v[j] = vn[j];
    }
    {
        float z31 = rdlane(zacc, 31), z63 = rdlane(zacc, 63);
        if (lane == 0) logZpart[wv] = z31 + z63;
    }
    __syncthreads();

    if (wv == 0) {
        float logZ = 0.0f;
        #pragma unroll
        for (int w = 0; w < 8; ++w) logZ += logZpart[w];
        const int labm1 = rol1_i(lab);
        const float mskip = (lane >= 1 && lab != labm1) ? 1.0f : 0.0f;
        const bool l0 = (lane == 0);

        float a0 = l0 ? qblank[0] : 0.0f;
        float a1 = l0 ? h2f(qtab[0][lane]) : 0.0f;
        float aX = 0.0f;
        int Esum = 0;

        float qbv[8], qlv[8];
        #pragma unroll
        for (int i = 0; i < 8; ++i) {
            qbv[i] = qblank[1 + i];
            qlv[i] = h2f(qtab[1 + i][lane]);
        }
        for (int t0 = 1; t0 + 8 <= TT; t0 += 8) {
            float qbn[8], qln[8];
            #pragma unroll
            for (int i = 0; i < 8; ++i) {
                int tn = t0 + 8 + i; tn = (tn < TT) ? tn : (TT - 1);
                qbn[i] = qblank[tn];
                qln[i] = h2f(qtab[tn][lane]);
            }
            #pragma unroll
            for (int i = 0; i < 8; ++i) {
                float nb  = rol1_f(a1);
                float na0 = (a0 + (l0 ? 0.0f : nb)) * qbv[i];
                float na1 = fmaf(mskip, nb, a0 + a1) * qlv[i];
                aX = l0 ? (aX + nb) * qbv[i] : 0.0f;
                a0 = na0; a1 = na1;
            }
            float m = fmaxf(fmaxf(a0, a1), aX);
            float mall = wave_max_bcast(m);
            int ex = (int)((__float_as_uint(mall) >> 23) & 0xFF);
            int e  = 127 - ex;
            float sc = __uint_as_float((unsigned)(127 + e) << 23);
            a0 *= sc; a1 *= sc; aX *= sc;
            Esum += e;
            #pragma unroll
            for (int i = 0; i < 8; ++i) { qbv[i] = qbn[i]; qlv[i] = qln[i]; }
        }
        #pragma unroll
        for (int i = 0; i < 7; ++i) {
            float nb  = rol1_f(a1);
            float na0 = (a0 + (l0 ? 0.0f : nb)) * qbv[i];
            float na1 = fmaf(mskip, nb, a0 + a1) * qlv[i];
            aX = l0 ? (aX + nb) * qbv[i] : 0.0f;
            a0 = na0; a1 = na1;
        }
        float a127 = rdlane(a1, 63);
        if (lane == 0) {
            out[b] = logZ + (float)Esum * 0.69314718055994531f - __logf(aX + a127);
        }
    }
}

extern "C" void kernel_launch(void* const* d_in, const int* in_sizes, int n_in,
                              void* d_out, int out_size, void* d_ws, size_t ws_size,
                              hipStream_t stream) {
    const int*   y_true = (const int*)d_in[0];
    const float* y_pred = (const float*)d_in[1];
    float*       out    = (float*)d_out;
    if (ws_size >= WS_NEEDED) {
        unsigned short* qt_g = (unsigned short*)d_ws;
        float* qb_g = (float*)((char*)d_ws + QB_OFF);
        float* lz_g = (float*)((char*)d_ws + LZ_OFF);
        ctc_stage_kernel<<<BATCH, 512, 0, stream>>>(y_true, y_pred, qt_g, qb_g, lz_g);
        ctc_dp_kernel<<<BATCH, 64, 0, stream>>>(y_true, qt_g, qb_g, lz_g, out);
    } else {
        ctc_fwd_kernel<<<BATCH, 512, 0, stream>>>(y_true, y_pred, out);
    }
}

// Round 10
// 37.256 us; speedup vs baseline: 1.6283x; 1.3179x over previous
//
#include <hip/hip_runtime.h>
#include <math.h>

// CTC forward loss, Keras ctc_batch_cost semantics.
// B=1024, T=256, C=128, L=64, S=2L+1=129, blank=C-1=127.
// Prob-domain forward DP (no per-step transcendentals), exact power-of-2
// rescale per 8-step chunk. Single kernel, producer-consumer:
//   waves 1-7 stream y_pred rows into an fp16 LDS q-table (float4 = 2 rows
//   per load, DPP half-wave row sums, packed-fp16 register-shuffle gather),
//   bumping an LDS chunk counter after each row-pair is visible;
//   wave 0 runs the register DP concurrently, polling chunk counters.
// Streamers NEVER wait on the DP wave (no barriers in the main loop).
#define BATCH 1024
#define TT    256
#define CC    128
#define LL    64
#define EPSV  (1e-7f)

typedef float f32x4 __attribute__((ext_vector_type(4)));
typedef __fp16 fp16x2 __attribute__((ext_vector_type(2)));

// DPP ctrl: row_shr:N = 0x110+N, row_bcast:15 = 0x142, row_bcast:31 = 0x143,
// wave_rol:1 = 0x134.
template <int CTRL>
__device__ __forceinline__ float dpp0(float x) {   // invalid lanes -> 0
    return __int_as_float(__builtin_amdgcn_update_dpp(0, __float_as_int(x), CTRL, 0xF, 0xF, true));
}
template <int CTRL>
__device__ __forceinline__ float dppS(float x) {   // invalid lanes -> self
    return __int_as_float(__builtin_amdgcn_update_dpp(__float_as_int(x), __float_as_int(x), CTRL, 0xF, 0xF, false));
}
__device__ __forceinline__ float rol1_f(float x) { // lane i <- lane (i-1)&63
    return __int_as_float(__builtin_amdgcn_update_dpp(__float_as_int(x), __float_as_int(x), 0x134, 0xF, 0xF, false));
}
__device__ __forceinline__ int rol1_i(int x) {
    return __builtin_amdgcn_update_dpp(x, x, 0x134, 0xF, 0xF, false);
}
__device__ __forceinline__ float rdlane(float x, int l) {
    return __int_as_float(__builtin_amdgcn_readlane(__float_as_int(x), l));
}
__device__ __forceinline__ float wave_max_bcast(float m) {
    m = fmaxf(m, dppS<0x111>(m));
    m = fmaxf(m, dppS<0x112>(m));
    m = fmaxf(m, dppS<0x114>(m));
    m = fmaxf(m, dppS<0x118>(m));
    m = fmaxf(m, dppS<0x142>(m));
    m = fmaxf(m, dppS<0x143>(m));
    return rdlane(m, 63);
}
__device__ __forceinline__ int pkrtz(float a, float b) { // 2xf32 -> packed f16 (RTZ), 1 instr
    fp16x2 h = __builtin_amdgcn_cvt_pkrtz(a, b);
    int r; __builtin_memcpy(&r, &h, 4);
    return r;
}
__device__ __forceinline__ float h2f(unsigned short u) {
    _Float16 h; __builtin_memcpy(&h, &u, 2);
    return (float)h;
}

__global__ __launch_bounds__(512, 8) void ctc_fwd_kernel(const int* __restrict__ y_true,
                                                         const float* __restrict__ y_pred,
                                                         float* __restrict__ out) {
    __shared__ unsigned short qtab[TT][66];  // q[t][l] = p[t][yt[l]]+eps (fp16 bits)
    __shared__ float qblank[TT];             // q[t][blank]
    __shared__ float logZpart[8];
    __shared__ int   chunkCnt[32];           // chunk c ready when == 4 (row-pairs 4c..4c+3)
    __shared__ int   doneCnt;                // streamer completion count (7 when done)

    const int b    = blockIdx.x;
    const int tid  = threadIdx.x;
    const int wv   = tid >> 6;
    const int lane = tid & 63;

    const float* yp = y_pred + (size_t)b * (TT * CC);
    const int lab  = y_true[b * LL + lane];  // lane l holds label l
    const int srcA = lab >> 2;
    const int srcB = 32 + srcA;
    const bool hiPair = (lab & 2) != 0;
    const bool hiHalf = (lab & 1) != 0;

    // float4 covers 2 rows: lanes 0-31 -> row 2*r2, lanes 32-63 -> row 2*r2+1.
    const int off = ((lane >> 5) << 7) + ((lane & 31) << 2);
    const float* base = yp + off;

    if (tid < 32) chunkCnt[tid] = 0;
    if (tid == 32) doneCnt = 0;
    __syncthreads();

    if (wv > 0) {
        // ================= streamers: waves 1-7, row-pairs r2 = (wv-1) + 7*i =================
        const int sw = wv - 1;               // 0..6
        float zacc = 0.0f;                   // meaningful on lanes 31 / 63
        f32x4 v[8];
        #pragma unroll
        for (int d = 0; d < 8; ++d) {
            int r2 = sw + 7 * d; r2 = (r2 < 128) ? r2 : 127;
            v[d] = *(const f32x4*)(base + 256 * r2);
        }
        #pragma unroll
        for (int i = 0; i < 19; ++i) {
            const int  r2i   = sw + 7 * i;
            const bool valid = (r2i < 128);
            const int  r2    = valid ? r2i : 127;
            f32x4 x = v[i & 7];
            if (i + 8 < 19) {
                int rn = sw + 7 * (i + 8); rn = (rn < 128) ? rn : 127;
                v[i & 7] = *(const f32x4*)(base + 256 * rn);
            }
            const int tA = 2 * r2, tB = tA + 1;
            float q0 = x[0] + EPSV, q1 = x[1] + EPSV;
            float q2 = x[2] + EPSV, q3 = x[3] + EPSV;
            // half-wave reduce: row-A total -> lane 31, row-B total -> lane 63
            float s = (q0 + q1) + (q2 + q3);
            s += dpp0<0x111>(s);
            s += dpp0<0x112>(s);
            s += dpp0<0x114>(s);
            s += dpp0<0x118>(s);
            s += dpp0<0x142>(s);
            if (valid) zacc += __logf(s);
            // pack own 4 cols to fp16 pairs, gather via register shuffles
            int i01 = pkrtz(q0, q1);
            int i23 = pkrtz(q2, q3);
            int gA01 = __shfl(i01, srcA), gA23 = __shfl(i23, srcA);
            int gB01 = __shfl(i01, srcB), gB23 = __shfl(i23, srcB);
            int sA = hiPair ? gA23 : gA01;
            int sB = hiPair ? gB23 : gB01;
            if (valid) {
                qtab[tA][lane] = (unsigned short)(hiHalf ? ((unsigned)sA >> 16) : (sA & 0xFFFF));
                qtab[tB][lane] = (unsigned short)(hiHalf ? ((unsigned)sB >> 16) : (sB & 0xFFFF));
                if ((lane & 31) == 31) qblank[tA + (lane >> 5)] = q3;  // col 127 == blank
                // make writes visible, then publish the row-pair
                asm volatile("s_waitcnt lgkmcnt(0)" ::: "memory");
                if (lane == 0) atomicAdd(&chunkCnt[r2 >> 2], 1);
            }
        }
        float z31 = rdlane(zacc, 31), z63 = rdlane(zacc, 63);
        if (lane == 0) {
            logZpart[wv] = z31 + z63;
            asm volatile("s_waitcnt lgkmcnt(0)" ::: "memory");
            atomicAdd(&doneCnt, 1);
        }
    } else {
        // ================= wave 0: register DP, consuming chunks as published =================
        const int   labm1 = rol1_i(lab);
        const float mskip = (lane >= 1 && lab != labm1) ? 1.0f : 0.0f;
        const bool  l0 = (lane == 0);

        volatile int* vcnt = chunkCnt;
        // chunk 0: rows 0..7
        while (vcnt[0] < 4) __builtin_amdgcn_s_sleep(1);
        __builtin_amdgcn_sched_barrier(0);

        // t=0 init: alpha[0]=q0[blank], alpha[1]=q0[yt[0]], rest 0.
        float a0 = l0 ? qblank[0] : 0.0f;           // even state 2*lane
        float a1 = l0 ? h2f(qtab[0][lane]) : 0.0f;  // odd state 2*lane+1
        float aX = 0.0f;                             // state 128 (lane 0 only)
        int Esum = 0;

        {   // steps t = 1..7 (rows in chunk 0)
            float qb8[8], ql8[8];
            #pragma unroll
            for (int i = 1; i < 8; ++i) { qb8[i] = qblank[i]; ql8[i] = h2f(qtab[i][lane]); }
            #pragma unroll
            for (int i = 1; i < 8; ++i) {
                float nb  = rol1_f(a1);              // alpha[2*lane-1]
                float na0 = (a0 + (l0 ? 0.0f : nb)) * qb8[i];
                float na1 = fmaf(mskip, nb, a0 + a1) * ql8[i];
                aX = l0 ? (aX + nb) * qb8[i] : 0.0f;
                a0 = na0; a1 = na1;
            }
            float mall = wave_max_bcast(fmaxf(fmaxf(a0, a1), aX));
            int e = 127 - (int)((__float_as_uint(mall) >> 23) & 0xFF);
            float sc = __uint_as_float((unsigned)(127 + e) << 23);
            a0 *= sc; a1 *= sc; aX *= sc;
            Esum += e;
        }
        for (int c = 1; c < 32; ++c) {               // chunks 1..31: steps 8c..8c+7
            while (vcnt[c] < 4) __builtin_amdgcn_s_sleep(1);
            __builtin_amdgcn_sched_barrier(0);
            float qb8[8], ql8[8];
            #pragma unroll
            for (int i = 0; i < 8; ++i) {
                const int t = 8 * c + i;
                qb8[i] = qblank[t];
                ql8[i] = h2f(qtab[t][lane]);
            }
            #pragma unroll
            for (int i = 0; i < 8; ++i) {
                float nb  = rol1_f(a1);
                float na0 = (a0 + (l0 ? 0.0f : nb)) * qb8[i];
                float na1 = fmaf(mskip, nb, a0 + a1) * ql8[i];
                aX = l0 ? (aX + nb) * qb8[i] : 0.0f;
                a0 = na0; a1 = na1;
            }
            float mall = wave_max_bcast(fmaxf(fmaxf(a0, a1), aX));  // exact pow2 rescale
            int e = 127 - (int)((__float_as_uint(mall) >> 23) & 0xFF);
            float sc = __uint_as_float((unsigned)(127 + e) << 23);
            a0 *= sc; a1 *= sc; aX *= sc;
            Esum += e;
        }
        // wait for all logZ partials, sum in fixed order
        volatile int* vd = &doneCnt;
        while (*vd < 7) __builtin_amdgcn_s_sleep(1);
        __builtin_amdgcn_sched_barrier(0);
        float LZ = 0.0f;
        #pragma unroll
        for (int w = 1; w < 8; ++w) LZ += logZpart[w];
        float a127 = rdlane(a1, 63);
        if (lane == 0) {
            out[b] = LZ + (float)Esum * 0.69314718055994531f - __logf(aX + a127);
        }
    }
}

extern "C" void kernel_launch(void* const* d_in, const int* in_sizes, int n_in,
                              void* d_out, int out_size, void* d_ws, size_t ws_size,
                              hipStream_t stream) {
    const int*   y_true = (const int*)d_in[0];
    const float* y_pred = (const float*)d_in[1];
    float*       out    = (float*)d_out;
    ctc_fwd_kernel<<<BATCH, 512, 0, stream>>>(y_true, y_pred, out);
}